// Round 2
// baseline (82.187 us; speedup 1.0000x reference)
//
#include <hip/hip_runtime.h>
#include <stdint.h>

// ---------------------------------------------------------------------------
// out[b,t,a,:] = (state_in[b,t,a,:] @ readin[session[b]]) @ project
// Factored: W_b = readin[session[b]] @ project  (192x256), out_b = X_b @ W_b.
// k1 builds W_t[b][o][i] (bf16, K-major) in d_ws.
// k2: batched GEMM, A (X, fp32) read direct global->reg (no LDS), B (W_t)
// staged once per block in swizzled LDS. One barrier total; 16 waves/CU.
// ---------------------------------------------------------------------------

typedef short    bf16x8 __attribute__((ext_vector_type(8)));
typedef float    f32x4  __attribute__((ext_vector_type(4)));
typedef uint32_t u32x4  __attribute__((ext_vector_type(4)));

#define NB    128   // batch
#define MPB   1024  // rows per batch = T*A
#define INF   192   // K of main GEMM
#define RDIM  64
#define OUTF  256

// round-to-nearest-even f32 -> bf16 bits
__device__ __forceinline__ uint16_t f2bf(float f) {
    union { float f; uint32_t u; } v; v.f = f;
    return (uint16_t)((v.u + 0x7fffu + ((v.u >> 16) & 1u)) >> 16);
}
__device__ __forceinline__ uint32_t pack2(float a, float b) {
    return (uint32_t)f2bf(a) | ((uint32_t)f2bf(b) << 16);
}
__device__ __forceinline__ bf16x8 cvt8(f32x4 a, f32x4 b) {
    u32x4 d;
    d[0] = pack2(a[0], a[1]); d[1] = pack2(a[2], a[3]);
    d[2] = pack2(b[0], b[1]); d[3] = pack2(b[2], b[3]);
    union { u32x4 u; bf16x8 h; } r; r.u = d;
    return r.h;
}

// global -> LDS direct copy, 16B per lane. LDS dest must be wave-uniform base.
__device__ __forceinline__ void gl_lds16(const void* g, void* l) {
    auto gp = (const __attribute__((address_space(1))) uint32_t*)(uintptr_t)g;
    auto lp = (__attribute__((address_space(3))) uint32_t*)(uintptr_t)l;
    __builtin_amdgcn_global_load_lds(gp, lp, 16, 0, 0);
}

// ---------------------------------------------------------------------------
// k1: W_t[b][o][i] = sum_h project[h][o] * readin[session[b]][i][h]
// grid 256 = (b:128) x (o-half:2); block 256 thr (4 waves, 2x2 wave grid)
// ---------------------------------------------------------------------------
__global__ __launch_bounds__(256) void k1_build_w(
    const float* __restrict__ readin,    // [512][192][64]
    const float* __restrict__ project,   // [64][256]
    const int*   __restrict__ session,   // [128]
    uint16_t*    __restrict__ Wt)        // [128][256][192] bf16 bits
{
    __shared__ uint16_t Rl[INF * 64];   // [i][h] bf16, XOR-swizzled, 24KB
    __shared__ uint16_t Pl[128 * 64];   // [o][h] bf16, XOR-swizzled, 16KB

    const int b  = blockIdx.x >> 1;
    const int oh = blockIdx.x & 1;
    const int t  = threadIdx.x;
    const float* Rg = readin + (size_t)session[b] * (INF * RDIM);

#pragma unroll
    for (int c = 0; c < 3; ++c) {
        int idx = c * 4096 + t * 16;       // linear into [192][64]
        int row = idx >> 6;
        int kg0 = (idx & 63) >> 3;
        f32x4 v0 = *(const f32x4*)(Rg + idx);
        f32x4 v1 = *(const f32x4*)(Rg + idx + 4);
        f32x4 v2 = *(const f32x4*)(Rg + idx + 8);
        f32x4 v3 = *(const f32x4*)(Rg + idx + 12);
        u32x4 d0, d1;
        d0[0] = pack2(v0[0], v0[1]); d0[1] = pack2(v0[2], v0[3]);
        d0[2] = pack2(v1[0], v1[1]); d0[3] = pack2(v1[2], v1[3]);
        d1[0] = pack2(v2[0], v2[1]); d1[1] = pack2(v2[2], v2[3]);
        d1[2] = pack2(v3[0], v3[1]); d1[3] = pack2(v3[2], v3[3]);
        *(u32x4*)&Rl[row * 64 + (((kg0    ) ^ (row & 7)) << 3)] = d0;
        *(u32x4*)&Rl[row * 64 + (((kg0 + 1) ^ (row & 7)) << 3)] = d1;
    }
    {
        int h  = t >> 2;
        int og = (t & 3) * 32;
        const float* Pg = project + (size_t)h * OUTF + oh * 128 + og;
#pragma unroll
        for (int q = 0; q < 8; ++q) {
            f32x4 v = *(const f32x4*)(Pg + q * 4);
#pragma unroll
            for (int e = 0; e < 4; ++e) {
                int o = og + q * 4 + e;
                Pl[o * 64 + (((h >> 3) ^ (o & 7)) << 3) + (h & 7)] = f2bf(v[e]);
            }
        }
    }
    __syncthreads();

    const int l  = t & 63, w = t >> 6;
    const int wm = w >> 1, wn = w & 1;
    const int lr = l & 15, lk = l >> 4;

    f32x4 acc[4][6];
#pragma unroll
    for (int m = 0; m < 4; ++m)
#pragma unroll
        for (int n = 0; n < 6; ++n) acc[m][n] = f32x4{0.f, 0.f, 0.f, 0.f};

#pragma unroll
    for (int kk = 0; kk < 2; ++kk) {
        int kg = kk * 4 + lk;
        bf16x8 a[4], bb[6];
#pragma unroll
        for (int m = 0; m < 4; ++m) {
            int row = wm * 64 + m * 16 + lr;
            a[m] = *(const bf16x8*)&Pl[row * 64 + ((kg ^ (row & 7)) << 3)];
        }
#pragma unroll
        for (int n = 0; n < 6; ++n) {
            int col = wn * 96 + n * 16 + lr;
            bb[n] = *(const bf16x8*)&Rl[col * 64 + ((kg ^ (col & 7)) << 3)];
        }
#pragma unroll
        for (int m = 0; m < 4; ++m)
#pragma unroll
            for (int n = 0; n < 6; ++n)
                acc[m][n] = __builtin_amdgcn_mfma_f32_16x16x32_bf16(
                    a[m], bb[n], acc[m][n], 0, 0, 0);
    }

    uint16_t* Wb = Wt + ((size_t)b * OUTF + oh * 128) * INF;
#pragma unroll
    for (int m = 0; m < 4; ++m) {
        int o = wm * 64 + m * 16 + lk * 4;
#pragma unroll
        for (int n = 0; n < 6; ++n) {
            int i = wn * 96 + n * 16 + lr;
#pragma unroll
            for (int j = 0; j < 4; ++j)
                Wb[(size_t)(o + j) * INF + i] = f2bf(acc[m][n][j]);
        }
    }
}

// ---------------------------------------------------------------------------
// k2: out tile 256(M) x 128(N) per block, 512 thr = 8 waves (4x2), wave 64x64.
// B staged once in swizzled LDS (48KB); A fp32 direct global->reg per K-step.
// Bs layout: row n (stride 384B), 24 slots of 16B; slot' = (s&24)|((s&7)^(n&7))
// Grid 1024 = b(128) x mt(4) x nt(2), XCD-swizzled.
// ---------------------------------------------------------------------------
__global__ __launch_bounds__(512, 4) void k2_gemm(
    const float*    __restrict__ X,    // [128][1024][192]
    const uint16_t* __restrict__ Wt,   // [128][256][192] bf16
    float*          __restrict__ Y)    // [128][1024][256]
{
    __shared__ uint16_t Bs[128 * INF];   // 48 KB

    // bijective XCD swizzle: 1024 % 8 == 0
    const int bid0 = blockIdx.x;
    const int bid  = ((bid0 & 7) << 7) | (bid0 >> 3);
    const int b  = bid >> 3;
    const int mt = (bid >> 1) & 3;
    const int nt = bid & 1;
    const int t  = threadIdx.x, l = t & 63, w = t >> 6;

    const float*    Xb = X  + ((size_t)b * MPB  + mt * 256) * INF;
    const uint16_t* Wb = Wt + ((size_t)b * OUTF + nt * 128) * INF;
    float*          Yb = Y  + ((size_t)b * MPB  + mt * 256) * OUTF + nt * 128;

    // ---- stage Bs: 48 x 1KB chunks; wave w handles chunks w*6 .. w*6+5 ----
#pragma unroll
    for (int j = 0; j < 6; ++j) {
        int c  = w * 6 + j;
        int p  = c * 1024 + l * 16;        // linear LDS byte position
        int n  = p / 384;                  // Bs row (384B per row)
        int sp = (p % 384) >> 4;           // swizzled 16B-slot 0..23
        int s  = (sp & 24) | ((sp & 7) ^ (n & 7));  // inverse swizzle
        gl_lds16(Wb + (size_t)n * INF + s * 8, &Bs[c * 512]);
    }
    __syncthreads();

    const int wm = w >> 1, wn = w & 1;     // wave grid 4(M) x 2(N)
    const int lr = l & 15, lk = l >> 4;

    f32x4 acc[4][4];
#pragma unroll
    for (int m = 0; m < 4; ++m)
#pragma unroll
        for (int n = 0; n < 4; ++n) acc[m][n] = f32x4{0.f, 0.f, 0.f, 0.f};

    // A row pointers: lane reads rows (wm*64 + m*16 + lr), k = ks*32 + lk*8
    const float* a0 = Xb + (size_t)(wm * 64 + lr) * INF + lk * 8;
    // B lds: row n_abs = wn*64 + n*16 + lr, slot s = ks*4 + lk
    const int nb[4] = { wn * 64 + lr, wn * 64 + 16 + lr,
                        wn * 64 + 32 + lr, wn * 64 + 48 + lr };

#pragma unroll
    for (int ks = 0; ks < 6; ++ks) {
        f32x4 pa[4][2];
#pragma unroll
        for (int m = 0; m < 4; ++m) {
            const float* p = a0 + (size_t)m * (16 * INF) + ks * 32;
            pa[m][0] = *(const f32x4*)(p);
            pa[m][1] = *(const f32x4*)(p + 4);
        }
        bf16x8 af[4], bf_[4];
#pragma unroll
        for (int m = 0; m < 4; ++m) af[m] = cvt8(pa[m][0], pa[m][1]);
        const int s   = ks * 4 + lk;
        const int grp = s & 24, low = s & 7;
#pragma unroll
        for (int n = 0; n < 4; ++n) {
            int na = nb[n];
            bf_[n] = *(const bf16x8*)&Bs[na * INF + ((grp | (low ^ (na & 7))) << 3)];
        }
#pragma unroll
        for (int m = 0; m < 4; ++m)
#pragma unroll
            for (int n = 0; n < 4; ++n)
                acc[m][n] = __builtin_amdgcn_mfma_f32_16x16x32_bf16(
                    af[m], bf_[n], acc[m][n], 0, 0, 0);
    }

    // epilogue: D row=(lane>>4)*4+j, col=lane&15
#pragma unroll
    for (int m = 0; m < 4; ++m) {
        int r0 = wm * 64 + m * 16 + lk * 4;
#pragma unroll
        for (int n = 0; n < 4; ++n) {
            int c0 = wn * 64 + n * 16 + lr;
#pragma unroll
            for (int j = 0; j < 4; ++j)
                Yb[(size_t)(r0 + j) * OUTF + c0] = acc[m][n][j];
        }
    }
}

extern "C" void kernel_launch(void* const* d_in, const int* in_sizes, int n_in,
                              void* d_out, int out_size, void* d_ws, size_t ws_size,
                              hipStream_t stream) {
    (void)in_sizes; (void)n_in; (void)out_size; (void)ws_size;
    const float* state   = (const float*)d_in[0];
    const int*   session = (const int*)  d_in[1];
    const float* readin  = (const float*)d_in[2];
    const float* project = (const float*)d_in[3];
    float*    out = (float*)d_out;
    uint16_t* Wt  = (uint16_t*)d_ws;   // 128*256*192*2 B = 12.6 MB scratch

    hipLaunchKernelGGL(k1_build_w, dim3(256), dim3(256), 0, stream,
                       readin, project, session, Wt);
    hipLaunchKernelGGL(k2_gemm, dim3(1024), dim3(512), 0, stream,
                       state, Wt, out);
}

// Round 3
// 75.705 us; speedup vs baseline: 1.0856x; 1.0856x over previous
//
#include <hip/hip_runtime.h>
#include <hip/hip_bf16.h>
#include <stdint.h>

// ---------------------------------------------------------------------------
// out[b,t,a,:] = (state_in[b,t,a,:] @ readin[session[b]]) @ project
// Factored: W_b = readin[session[b]] @ project  (192x256), out_b = X_b @ W_b.
// k1 builds W_t[b][o][i] (bf16, K-major) in d_ws.
// k2: batched GEMM, A (X, fp32) global->reg with 1-deep SW prefetch,
// B (W_t) staged once per block in swizzled LDS. One barrier total.
// ---------------------------------------------------------------------------

typedef short    bf16x8 __attribute__((ext_vector_type(8)));
typedef float    f32x4  __attribute__((ext_vector_type(4)));
typedef uint32_t u32x4  __attribute__((ext_vector_type(4)));

#define NB    128   // batch
#define MPB   1024  // rows per batch = T*A
#define INF   192   // K of main GEMM
#define RDIM  64
#define OUTF  256

// round-to-nearest-even f32 -> bf16 bits (scalar path, used in k1)
__device__ __forceinline__ uint16_t f2bf(float f) {
    union { float f; uint32_t u; } v; v.f = f;
    return (uint16_t)((v.u + 0x7fffu + ((v.u >> 16) & 1u)) >> 16);
}
__device__ __forceinline__ uint32_t pack2(float a, float b) {
    return (uint32_t)f2bf(a) | ((uint32_t)f2bf(b) << 16);
}

// packed f32x8 -> bf16x8 via __float22bfloat162_rn (v_cvt_pk_bf16_f32)
__device__ __forceinline__ bf16x8 cvt8(f32x4 a, f32x4 b) {
    union { __hip_bfloat162 h2[4]; bf16x8 h; } r;
    r.h2[0] = __float22bfloat162_rn({a[0], a[1]});
    r.h2[1] = __float22bfloat162_rn({a[2], a[3]});
    r.h2[2] = __float22bfloat162_rn({b[0], b[1]});
    r.h2[3] = __float22bfloat162_rn({b[2], b[3]});
    return r.h;
}

// global -> LDS direct copy, 16B per lane. LDS dest must be wave-uniform base.
__device__ __forceinline__ void gl_lds16(const void* g, void* l) {
    auto gp = (const __attribute__((address_space(1))) uint32_t*)(uintptr_t)g;
    auto lp = (__attribute__((address_space(3))) uint32_t*)(uintptr_t)l;
    __builtin_amdgcn_global_load_lds(gp, lp, 16, 0, 0);
}

// ---------------------------------------------------------------------------
// k1: W_t[b][o][i] = sum_h project[h][o] * readin[session[b]][i][h]
// grid 256 = (b:128) x (o-half:2); block 256 thr (4 waves, 2x2 wave grid)
// ---------------------------------------------------------------------------
__global__ __launch_bounds__(256) void k1_build_w(
    const float* __restrict__ readin,    // [512][192][64]
    const float* __restrict__ project,   // [64][256]
    const int*   __restrict__ session,   // [128]
    uint16_t*    __restrict__ Wt)        // [128][256][192] bf16 bits
{
    __shared__ uint16_t Rl[INF * 64];   // [i][h] bf16, XOR-swizzled, 24KB
    __shared__ uint16_t Pl[128 * 64];   // [o][h] bf16, XOR-swizzled, 16KB

    const int b  = blockIdx.x >> 1;
    const int oh = blockIdx.x & 1;
    const int t  = threadIdx.x;
    const float* Rg = readin + (size_t)session[b] * (INF * RDIM);

#pragma unroll
    for (int c = 0; c < 3; ++c) {
        int idx = c * 4096 + t * 16;       // linear into [192][64]
        int row = idx >> 6;
        int kg0 = (idx & 63) >> 3;
        f32x4 v0 = *(const f32x4*)(Rg + idx);
        f32x4 v1 = *(const f32x4*)(Rg + idx + 4);
        f32x4 v2 = *(const f32x4*)(Rg + idx + 8);
        f32x4 v3 = *(const f32x4*)(Rg + idx + 12);
        u32x4 d0, d1;
        d0[0] = pack2(v0[0], v0[1]); d0[1] = pack2(v0[2], v0[3]);
        d0[2] = pack2(v1[0], v1[1]); d0[3] = pack2(v1[2], v1[3]);
        d1[0] = pack2(v2[0], v2[1]); d1[1] = pack2(v2[2], v2[3]);
        d1[2] = pack2(v3[0], v3[1]); d1[3] = pack2(v3[2], v3[3]);
        *(u32x4*)&Rl[row * 64 + (((kg0    ) ^ (row & 7)) << 3)] = d0;
        *(u32x4*)&Rl[row * 64 + (((kg0 + 1) ^ (row & 7)) << 3)] = d1;
    }
    {
        int h  = t >> 2;
        int og = (t & 3) * 32;
        const float* Pg = project + (size_t)h * OUTF + oh * 128 + og;
#pragma unroll
        for (int q = 0; q < 8; ++q) {
            f32x4 v = *(const f32x4*)(Pg + q * 4);
#pragma unroll
            for (int e = 0; e < 4; ++e) {
                int o = og + q * 4 + e;
                Pl[o * 64 + (((h >> 3) ^ (o & 7)) << 3) + (h & 7)] = f2bf(v[e]);
            }
        }
    }
    __syncthreads();

    const int l  = t & 63, w = t >> 6;
    const int wm = w >> 1, wn = w & 1;
    const int lr = l & 15, lk = l >> 4;

    f32x4 acc[4][6];
#pragma unroll
    for (int m = 0; m < 4; ++m)
#pragma unroll
        for (int n = 0; n < 6; ++n) acc[m][n] = f32x4{0.f, 0.f, 0.f, 0.f};

#pragma unroll
    for (int kk = 0; kk < 2; ++kk) {
        int kg = kk * 4 + lk;
        bf16x8 a[4], bb[6];
#pragma unroll
        for (int m = 0; m < 4; ++m) {
            int row = wm * 64 + m * 16 + lr;
            a[m] = *(const bf16x8*)&Pl[row * 64 + ((kg ^ (row & 7)) << 3)];
        }
#pragma unroll
        for (int n = 0; n < 6; ++n) {
            int col = wn * 96 + n * 16 + lr;
            bb[n] = *(const bf16x8*)&Rl[col * 64 + ((kg ^ (col & 7)) << 3)];
        }
#pragma unroll
        for (int m = 0; m < 4; ++m)
#pragma unroll
            for (int n = 0; n < 6; ++n)
                acc[m][n] = __builtin_amdgcn_mfma_f32_16x16x32_bf16(
                    a[m], bb[n], acc[m][n], 0, 0, 0);
    }

    uint16_t* Wb = Wt + ((size_t)b * OUTF + oh * 128) * INF;
#pragma unroll
    for (int m = 0; m < 4; ++m) {
        int o = wm * 64 + m * 16 + lk * 4;
#pragma unroll
        for (int n = 0; n < 6; ++n) {
            int i = wn * 96 + n * 16 + lr;
#pragma unroll
            for (int j = 0; j < 4; ++j)
                Wb[(size_t)(o + j) * INF + i] = f2bf(acc[m][n][j]);
        }
    }
}

// ---------------------------------------------------------------------------
// k2: out tile 256(M) x 128(N) per block, 512 thr = 8 waves (4x2), wave 64x64.
// B staged once in swizzled LDS (48KB); A fp32 global->reg, 1-deep prefetch.
// Bs layout: row n (stride 384B), 24 slots of 16B; slot' = (s&24)|((s&7)^(n&7))
// Grid 1024 = b(128) x mt(4) x nt(2), XCD-swizzled (bijective: 1024%8==0).
// ---------------------------------------------------------------------------
__global__ __launch_bounds__(512, 4) void k2_gemm(
    const float*    __restrict__ X,    // [128][1024][192]
    const uint16_t* __restrict__ Wt,   // [128][256][192] bf16
    float*          __restrict__ Y)    // [128][1024][256]
{
    __shared__ uint16_t Bs[128 * INF];   // 48 KB

    const int bid0 = blockIdx.x;
    const int bid  = ((bid0 & 7) << 7) | (bid0 >> 3);
    const int b  = bid >> 3;
    const int mt = (bid >> 1) & 3;
    const int nt = bid & 1;
    const int t  = threadIdx.x, l = t & 63, w = t >> 6;

    const float*    Xb = X  + ((size_t)b * MPB  + mt * 256) * INF;
    const uint16_t* Wb = Wt + ((size_t)b * OUTF + nt * 128) * INF;
    float*          Yb = Y  + ((size_t)b * MPB  + mt * 256) * OUTF + nt * 128;

    // ---- stage Bs: 48 x 1KB chunks; wave w handles chunks w*6 .. w*6+5 ----
#pragma unroll
    for (int j = 0; j < 6; ++j) {
        int c  = w * 6 + j;
        int p  = c * 1024 + l * 16;        // linear LDS byte position
        int n  = p / 384;                  // Bs row (384B per row)
        int sp = (p % 384) >> 4;           // swizzled 16B-slot 0..23
        int s  = (sp & 24) | ((sp & 7) ^ (n & 7));  // inverse swizzle
        gl_lds16(Wb + (size_t)n * INF + s * 8, &Bs[c * 512]);
    }

    const int wm = w >> 1, wn = w & 1;     // wave grid 4(M) x 2(N)
    const int lr = l & 15, lk = l >> 4;

    // A row base: lane reads rows (wm*64 + m*16 + lr), k = ks*32 + lk*8
    const float* a0 = Xb + (size_t)(wm * 64 + lr) * INF + lk * 8;
    const int nb[4] = { wn * 64 + lr, wn * 64 + 16 + lr,
                        wn * 64 + 32 + lr, wn * 64 + 48 + lr };

    f32x4 acc[4][4];
#pragma unroll
    for (int m = 0; m < 4; ++m)
#pragma unroll
        for (int n = 0; n < 4; ++n) acc[m][n] = f32x4{0.f, 0.f, 0.f, 0.f};

    // 1-deep software prefetch of A into named register buffers
    f32x4 pa0[4][2], pa1[4][2];
#pragma unroll
    for (int m = 0; m < 4; ++m) {
        const float* p = a0 + (size_t)m * (16 * INF);
        pa0[m][0] = *(const f32x4*)(p);
        pa0[m][1] = *(const f32x4*)(p + 4);
    }

    __syncthreads();   // Bs ready (gl_lds waits folded by compiler)

#pragma unroll
    for (int ks = 0; ks < 6; ++ks) {
        // issue next-step A loads into the other buffer
        if (ks < 5) {
#pragma unroll
            for (int m = 0; m < 4; ++m) {
                const float* p = a0 + (size_t)m * (16 * INF) + (ks + 1) * 32;
                if (ks & 1) { pa0[m][0] = *(const f32x4*)(p); pa0[m][1] = *(const f32x4*)(p + 4); }
                else        { pa1[m][0] = *(const f32x4*)(p); pa1[m][1] = *(const f32x4*)(p + 4); }
            }
        }
        // convert current buffer
        bf16x8 af[4], bf_[4];
#pragma unroll
        for (int m = 0; m < 4; ++m)
            af[m] = (ks & 1) ? cvt8(pa1[m][0], pa1[m][1])
                             : cvt8(pa0[m][0], pa0[m][1]);
        const int s   = ks * 4 + lk;
        const int grp = s & 24, low = s & 7;
#pragma unroll
        for (int n = 0; n < 4; ++n) {
            int na = nb[n];
            bf_[n] = *(const bf16x8*)&Bs[na * INF + ((grp | (low ^ (na & 7))) << 3)];
        }
#pragma unroll
        for (int m = 0; m < 4; ++m)
#pragma unroll
            for (int n = 0; n < 4; ++n)
                acc[m][n] = __builtin_amdgcn_mfma_f32_16x16x32_bf16(
                    af[m], bf_[n], acc[m][n], 0, 0, 0);
    }

    // epilogue: D row=(lane>>4)*4+j, col=lane&15
#pragma unroll
    for (int m = 0; m < 4; ++m) {
        int r0 = wm * 64 + m * 16 + lk * 4;
#pragma unroll
        for (int n = 0; n < 4; ++n) {
            int c0 = wn * 64 + n * 16 + lr;
#pragma unroll
            for (int j = 0; j < 4; ++j)
                Yb[(size_t)(r0 + j) * OUTF + c0] = acc[m][n][j];
        }
    }
}

extern "C" void kernel_launch(void* const* d_in, const int* in_sizes, int n_in,
                              void* d_out, int out_size, void* d_ws, size_t ws_size,
                              hipStream_t stream) {
    (void)in_sizes; (void)n_in; (void)out_size; (void)ws_size;
    const float* state   = (const float*)d_in[0];
    const int*   session = (const int*)  d_in[1];
    const float* readin  = (const float*)d_in[2];
    const float* project = (const float*)d_in[3];
    float*    out = (float*)d_out;
    uint16_t* Wt  = (uint16_t*)d_ws;   // 128*256*192*2 B = 12.6 MB scratch

    hipLaunchKernelGGL(k1_build_w, dim3(256), dim3(256), 0, stream,
                       readin, project, session, Wt);
    hipLaunchKernelGGL(k2_gemm, dim3(1024), dim3(512), 0, stream,
                       state, Wt, out);
}

// Round 4
// 55.715 us; speedup vs baseline: 1.4751x; 1.3588x over previous
//
#include <hip/hip_runtime.h>
#include <hip/hip_bf16.h>
#include <stdint.h>

// ---------------------------------------------------------------------------
// out[b,t,a,:] = (state_in[b,t,a,:] @ readin[session[b]]) @ project
// Factored: W_b = readin[session[b]] @ project  (192x256), out_b = X_b @ W_b.
// k1 builds W_t[b][o][i] (bf16, K-major) in d_ws.
// k2: m97-style batched GEMM. A (f32) and B (bf16) double-buffered in LDS via
// fire-and-forget global_load_lds; A rows padded to 144B for uniform banks;
// f32->bf16 conversion after LDS read. 52KB LDS -> 3 blocks/CU.
// ---------------------------------------------------------------------------

typedef short    bf16x8 __attribute__((ext_vector_type(8)));
typedef float    f32x4  __attribute__((ext_vector_type(4)));
typedef uint32_t u32x4  __attribute__((ext_vector_type(4)));

#define NB    128   // batch
#define MPB   1024  // rows per batch = T*A
#define INF   192   // K of main GEMM
#define RDIM  64
#define OUTF  256

// round-to-nearest-even f32 -> bf16 bits (scalar path, used in k1)
__device__ __forceinline__ uint16_t f2bf(float f) {
    union { float f; uint32_t u; } v; v.f = f;
    return (uint16_t)((v.u + 0x7fffu + ((v.u >> 16) & 1u)) >> 16);
}
__device__ __forceinline__ uint32_t pack2(float a, float b) {
    return (uint32_t)f2bf(a) | ((uint32_t)f2bf(b) << 16);
}

// packed f32x8 -> bf16x8 via __float22bfloat162_rn (v_cvt_pk_bf16_f32)
__device__ __forceinline__ bf16x8 cvt8(f32x4 a, f32x4 b) {
    union { __hip_bfloat162 h2[4]; bf16x8 h; } r;
    r.h2[0] = __float22bfloat162_rn({a[0], a[1]});
    r.h2[1] = __float22bfloat162_rn({a[2], a[3]});
    r.h2[2] = __float22bfloat162_rn({b[0], b[1]});
    r.h2[3] = __float22bfloat162_rn({b[2], b[3]});
    return r.h;
}

// global -> LDS direct copy, 16B per lane. LDS dest must be wave-uniform base.
__device__ __forceinline__ void gl_lds16(const void* g, void* l) {
    auto gp = (const __attribute__((address_space(1))) uint32_t*)(uintptr_t)g;
    auto lp = (__attribute__((address_space(3))) uint32_t*)(uintptr_t)l;
    __builtin_amdgcn_global_load_lds(gp, lp, 16, 0, 0);
}

// ---------------------------------------------------------------------------
// k1: W_t[b][o][i] = sum_h project[h][o] * readin[session[b]][i][h]
// grid 256 = (b:128) x (o-half:2); block 256 thr (4 waves, 2x2 wave grid)
// (unchanged from R1; proven correct, small cost)
// ---------------------------------------------------------------------------
__global__ __launch_bounds__(256) void k1_build_w(
    const float* __restrict__ readin,    // [512][192][64]
    const float* __restrict__ project,   // [64][256]
    const int*   __restrict__ session,   // [128]
    uint16_t*    __restrict__ Wt)        // [128][256][192] bf16 bits
{
    __shared__ uint16_t Rl[INF * 64];   // [i][h] bf16, XOR-swizzled, 24KB
    __shared__ uint16_t Pl[128 * 64];   // [o][h] bf16, XOR-swizzled, 16KB

    const int b  = blockIdx.x >> 1;
    const int oh = blockIdx.x & 1;
    const int t  = threadIdx.x;
    const float* Rg = readin + (size_t)session[b] * (INF * RDIM);

#pragma unroll
    for (int c = 0; c < 3; ++c) {
        int idx = c * 4096 + t * 16;       // linear into [192][64]
        int row = idx >> 6;
        int kg0 = (idx & 63) >> 3;
        f32x4 v0 = *(const f32x4*)(Rg + idx);
        f32x4 v1 = *(const f32x4*)(Rg + idx + 4);
        f32x4 v2 = *(const f32x4*)(Rg + idx + 8);
        f32x4 v3 = *(const f32x4*)(Rg + idx + 12);
        u32x4 d0, d1;
        d0[0] = pack2(v0[0], v0[1]); d0[1] = pack2(v0[2], v0[3]);
        d0[2] = pack2(v1[0], v1[1]); d0[3] = pack2(v1[2], v1[3]);
        d1[0] = pack2(v2[0], v2[1]); d1[1] = pack2(v2[2], v2[3]);
        d1[2] = pack2(v3[0], v3[1]); d1[3] = pack2(v3[2], v3[3]);
        *(u32x4*)&Rl[row * 64 + (((kg0    ) ^ (row & 7)) << 3)] = d0;
        *(u32x4*)&Rl[row * 64 + (((kg0 + 1) ^ (row & 7)) << 3)] = d1;
    }
    {
        int h  = t >> 2;
        int og = (t & 3) * 32;
        const float* Pg = project + (size_t)h * OUTF + oh * 128 + og;
#pragma unroll
        for (int q = 0; q < 8; ++q) {
            f32x4 v = *(const f32x4*)(Pg + q * 4);
#pragma unroll
            for (int e = 0; e < 4; ++e) {
                int o = og + q * 4 + e;
                Pl[o * 64 + (((h >> 3) ^ (o & 7)) << 3) + (h & 7)] = f2bf(v[e]);
            }
        }
    }
    __syncthreads();

    const int l  = t & 63, w = t >> 6;
    const int wm = w >> 1, wn = w & 1;
    const int lr = l & 15, lk = l >> 4;

    f32x4 acc[4][6];
#pragma unroll
    for (int m = 0; m < 4; ++m)
#pragma unroll
        for (int n = 0; n < 6; ++n) acc[m][n] = f32x4{0.f, 0.f, 0.f, 0.f};

#pragma unroll
    for (int kk = 0; kk < 2; ++kk) {
        int kg = kk * 4 + lk;
        bf16x8 a[4], bb[6];
#pragma unroll
        for (int m = 0; m < 4; ++m) {
            int row = wm * 64 + m * 16 + lr;
            a[m] = *(const bf16x8*)&Pl[row * 64 + ((kg ^ (row & 7)) << 3)];
        }
#pragma unroll
        for (int n = 0; n < 6; ++n) {
            int col = wn * 96 + n * 16 + lr;
            bb[n] = *(const bf16x8*)&Rl[col * 64 + ((kg ^ (col & 7)) << 3)];
        }
#pragma unroll
        for (int m = 0; m < 4; ++m)
#pragma unroll
            for (int n = 0; n < 6; ++n)
                acc[m][n] = __builtin_amdgcn_mfma_f32_16x16x32_bf16(
                    a[m], bb[n], acc[m][n], 0, 0, 0);
    }

    uint16_t* Wb = Wt + ((size_t)b * OUTF + oh * 128) * INF;
#pragma unroll
    for (int m = 0; m < 4; ++m) {
        int o = wm * 64 + m * 16 + lk * 4;
#pragma unroll
        for (int n = 0; n < 6; ++n) {
            int i = wn * 96 + n * 16 + lr;
#pragma unroll
            for (int j = 0; j < 4; ++j)
                Wb[(size_t)(o + j) * INF + i] = f2bf(acc[m][n][j]);
        }
    }
}

// ---------------------------------------------------------------------------
// k2: 128(M) x 128(N) tile, 256 thr = 4 waves (2x2), wave 64x64, BK=32.
// As[2]: 128 rows x 144B (128B data + 16B pad -> +4-bank shift/row, uniform
//        bank load). Staged via gl_lds in 18x1KB chunks (row = u/9 mapping;
//        pad unit fetches a duplicate). f32 -> cvt8 after ds_read.
// Bs[2]: 128 rows x 32 bf16 (64B rows -> natural 16-bank shift, no swizzle),
//        staged via gl_lds in 8x1KB chunks.
// One barrier per K-step; 52KB LDS -> 3 blocks/CU.
// Grid 2048 = b(128) x mt(8) x nt(2), bijective XCD swizzle (2048%8==0).
// ---------------------------------------------------------------------------
#define A_STRIDE 144           // bytes per As row
#define A_CHUNKS 18            // 18KB per buffer
#define B_CHUNKS 8             // 8KB per buffer

__global__ __launch_bounds__(256, 3) void k2_gemm(
    const float*    __restrict__ X,    // [128][1024][192]
    const uint16_t* __restrict__ Wt,   // [128][256][192] bf16
    float*          __restrict__ Y)    // [128][1024][256]
{
    __shared__ uint8_t  As[2][A_CHUNKS * 1024];  // 2 x 18KB
    __shared__ uint16_t Bs[2][B_CHUNKS * 512];   // 2 x 8KB

    const int bid0 = blockIdx.x;
    const int bid  = ((bid0 & 7) << 8) | (bid0 >> 3);   // XCD swizzle
    const int b  = bid >> 4;
    const int mt = (bid >> 1) & 7;
    const int nt = bid & 1;
    const int t  = threadIdx.x, l = t & 63, w = t >> 6;

    const float*    Xb = X  + ((size_t)b * MPB  + mt * 128) * INF;
    const uint16_t* Wb = Wt + ((size_t)b * OUTF + nt * 128) * INF;
    float*          Yb = Y  + ((size_t)b * MPB  + mt * 128) * OUTF + nt * 128;

    // ---- precompute A-chunk source offsets (this wave handles c = j*4+w) ----
    int aoff[5];                        // float offset into Xb (k=0)
    bool avalid[5];
    int achunk[5];
#pragma unroll
    for (int j = 0; j < 5; ++j) {
        int c = j * 4 + w;
        achunk[j] = c;
        avalid[j] = (c < A_CHUNKS);
        int u    = c * 64 + l;          // 16B-unit index, 9 units per row
        int row  = u / 9;
        int unit = u - row * 9;
        aoff[j] = row * INF + (unit < 8 ? unit * 4 : 0);
    }
    // B chunks: c = j*4+w for j in {0,1}; row = c*16 + (l>>2), slot l&3
    int boff[2];
#pragma unroll
    for (int j = 0; j < 2; ++j) {
        int c = j * 4 + w;
        boff[j] = (c * 16 + (l >> 2)) * INF + (l & 3) * 8;
    }

    auto stageA = [&](int ks, int buf) {
#pragma unroll
        for (int j = 0; j < 5; ++j)
            if (avalid[j])
                gl_lds16(Xb + aoff[j] + ks * 32, &As[buf][achunk[j] * 1024]);
    };
    auto stageB = [&](int ks, int buf) {
#pragma unroll
        for (int j = 0; j < 2; ++j)
            gl_lds16(Wb + boff[j] + ks * 32, &Bs[buf][(j * 4 + w) * 512]);
    };

    stageA(0, 0);
    stageB(0, 0);

    const int wm = w >> 1, wn = w & 1;     // wave grid 2(M) x 2(N)
    const int lr = l & 15, lk = l >> 4;

    f32x4 acc[4][4];
#pragma unroll
    for (int m = 0; m < 4; ++m)
#pragma unroll
        for (int n = 0; n < 4; ++n) acc[m][n] = f32x4{0.f, 0.f, 0.f, 0.f};

    __syncthreads();   // As[0]/Bs[0] ready (compiler drains vmcnt)

#pragma unroll
    for (int ks = 0; ks < 6; ++ks) {
        const int cur = ks & 1;
        if (ks < 5) { stageA(ks + 1, cur ^ 1); stageB(ks + 1, cur ^ 1); }

        bf16x8 af[4], bfr[4];
#pragma unroll
        for (int m = 0; m < 4; ++m) {
            int row = wm * 64 + m * 16 + lr;
            const uint8_t* p = &As[cur][row * A_STRIDE + lk * 32];
            f32x4 lo = *(const f32x4*)(p);
            f32x4 hi = *(const f32x4*)(p + 16);
            af[m] = cvt8(lo, hi);
        }
#pragma unroll
        for (int n = 0; n < 4; ++n) {
            int rn = wn * 64 + n * 16 + lr;
            bfr[n] = *(const bf16x8*)&Bs[cur][rn * 32 + lk * 8];
        }
#pragma unroll
        for (int m = 0; m < 4; ++m)
#pragma unroll
            for (int n = 0; n < 4; ++n)
                acc[m][n] = __builtin_amdgcn_mfma_f32_16x16x32_bf16(
                    af[m], bfr[n], acc[m][n], 0, 0, 0);

        __syncthreads();   // next buffers ready / current safe to overwrite
    }

    // epilogue: D row=(lane>>4)*4+j, col=lane&15
#pragma unroll
    for (int m = 0; m < 4; ++m) {
        int r0 = wm * 64 + m * 16 + lk * 4;
#pragma unroll
        for (int n = 0; n < 4; ++n) {
            int c0 = wn * 64 + n * 16 + lr;
#pragma unroll
            for (int j = 0; j < 4; ++j)
                Yb[(size_t)(r0 + j) * OUTF + c0] = acc[m][n][j];
        }
    }
}

extern "C" void kernel_launch(void* const* d_in, const int* in_sizes, int n_in,
                              void* d_out, int out_size, void* d_ws, size_t ws_size,
                              hipStream_t stream) {
    (void)in_sizes; (void)n_in; (void)out_size; (void)ws_size;
    const float* state   = (const float*)d_in[0];
    const int*   session = (const int*)  d_in[1];
    const float* readin  = (const float*)d_in[2];
    const float* project = (const float*)d_in[3];
    float*    out = (float*)d_out;
    uint16_t* Wt  = (uint16_t*)d_ws;   // 128*256*192*2 B = 12.6 MB scratch

    hipLaunchKernelGGL(k1_build_w, dim3(256), dim3(256), 0, stream,
                       readin, project, session, Wt);
    hipLaunchKernelGGL(k2_gemm, dim3(2048), dim3(256), 0, stream,
                       state, Wt, out);
}

// Round 5
// 54.039 us; speedup vs baseline: 1.5209x; 1.0310x over previous
//
#include <hip/hip_runtime.h>
#include <hip/hip_bf16.h>
#include <stdint.h>

// ---------------------------------------------------------------------------
// out[b,t,a,:] = (state_in[b,t,a,:] @ readin[session[b]]) @ project
// Factored: W_b = readin[session[b]] @ project  (192x256), out_b = X_b @ W_b.
// k1 builds W_t[b][o][i] (bf16, K-major) in d_ws.
// k2: 128x128 tile, BK=32, 3-buffer depth-2 pipeline with counted vmcnt(6)
// and raw s_barrier (1 barrier/step). A: XOR-8 swizzled f32 LDS (16KB/step),
// B: XOR-4 swizzled bf16 LDS (8KB/step); both staged via global_load_lds with
// pre-swizzled global source (both-sides-or-neither). 72KB LDS, 2 blocks/CU.
// ---------------------------------------------------------------------------

typedef short    bf16x8 __attribute__((ext_vector_type(8)));
typedef float    f32x4  __attribute__((ext_vector_type(4)));
typedef uint32_t u32x4  __attribute__((ext_vector_type(4)));

#define NB    128   // batch
#define MPB   1024  // rows per batch = T*A
#define INF   192   // K of main GEMM
#define RDIM  64
#define OUTF  256

#define WAIT_VM6() asm volatile("s_waitcnt vmcnt(6)" ::: "memory")
#define WAIT_VM0() asm volatile("s_waitcnt vmcnt(0)" ::: "memory")

// round-to-nearest-even f32 -> bf16 bits (scalar path, used in k1)
__device__ __forceinline__ uint16_t f2bf(float f) {
    union { float f; uint32_t u; } v; v.f = f;
    return (uint16_t)((v.u + 0x7fffu + ((v.u >> 16) & 1u)) >> 16);
}
__device__ __forceinline__ uint32_t pack2(float a, float b) {
    return (uint32_t)f2bf(a) | ((uint32_t)f2bf(b) << 16);
}

// packed f32x8 -> bf16x8 via __float22bfloat162_rn (v_cvt_pk_bf16_f32)
__device__ __forceinline__ bf16x8 cvt8(f32x4 a, f32x4 b) {
    union { __hip_bfloat162 h2[4]; bf16x8 h; } r;
    r.h2[0] = __float22bfloat162_rn({a[0], a[1]});
    r.h2[1] = __float22bfloat162_rn({a[2], a[3]});
    r.h2[2] = __float22bfloat162_rn({b[0], b[1]});
    r.h2[3] = __float22bfloat162_rn({b[2], b[3]});
    return r.h;
}

// global -> LDS direct copy, 16B per lane. LDS dest must be wave-uniform base.
__device__ __forceinline__ void gl_lds16(const void* g, void* l) {
    auto gp = (const __attribute__((address_space(1))) uint32_t*)(uintptr_t)g;
    auto lp = (__attribute__((address_space(3))) uint32_t*)(uintptr_t)l;
    __builtin_amdgcn_global_load_lds(gp, lp, 16, 0, 0);
}

// ---------------------------------------------------------------------------
// k1: W_t[b][o][i] = sum_h project[h][o] * readin[session[b]][i][h]
// grid 256 = (b:128) x (o-half:2); block 256 thr (4 waves, 2x2 wave grid)
// (unchanged; proven correct, small cost)
// ---------------------------------------------------------------------------
__global__ __launch_bounds__(256) void k1_build_w(
    const float* __restrict__ readin,    // [512][192][64]
    const float* __restrict__ project,   // [64][256]
    const int*   __restrict__ session,   // [128]
    uint16_t*    __restrict__ Wt)        // [128][256][192] bf16 bits
{
    __shared__ uint16_t Rl[INF * 64];   // [i][h] bf16, XOR-swizzled, 24KB
    __shared__ uint16_t Pl[128 * 64];   // [o][h] bf16, XOR-swizzled, 16KB

    const int b  = blockIdx.x >> 1;
    const int oh = blockIdx.x & 1;
    const int t  = threadIdx.x;
    const float* Rg = readin + (size_t)session[b] * (INF * RDIM);

#pragma unroll
    for (int c = 0; c < 3; ++c) {
        int idx = c * 4096 + t * 16;       // linear into [192][64]
        int row = idx >> 6;
        int kg0 = (idx & 63) >> 3;
        f32x4 v0 = *(const f32x4*)(Rg + idx);
        f32x4 v1 = *(const f32x4*)(Rg + idx + 4);
        f32x4 v2 = *(const f32x4*)(Rg + idx + 8);
        f32x4 v3 = *(const f32x4*)(Rg + idx + 12);
        u32x4 d0, d1;
        d0[0] = pack2(v0[0], v0[1]); d0[1] = pack2(v0[2], v0[3]);
        d0[2] = pack2(v1[0], v1[1]); d0[3] = pack2(v1[2], v1[3]);
        d1[0] = pack2(v2[0], v2[1]); d1[1] = pack2(v2[2], v2[3]);
        d1[2] = pack2(v3[0], v3[1]); d1[3] = pack2(v3[2], v3[3]);
        *(u32x4*)&Rl[row * 64 + (((kg0    ) ^ (row & 7)) << 3)] = d0;
        *(u32x4*)&Rl[row * 64 + (((kg0 + 1) ^ (row & 7)) << 3)] = d1;
    }
    {
        int h  = t >> 2;
        int og = (t & 3) * 32;
        const float* Pg = project + (size_t)h * OUTF + oh * 128 + og;
#pragma unroll
        for (int q = 0; q < 8; ++q) {
            f32x4 v = *(const f32x4*)(Pg + q * 4);
#pragma unroll
            for (int e = 0; e < 4; ++e) {
                int o = og + q * 4 + e;
                Pl[o * 64 + (((h >> 3) ^ (o & 7)) << 3) + (h & 7)] = f2bf(v[e]);
            }
        }
    }
    __syncthreads();

    const int l  = t & 63, w = t >> 6;
    const int wm = w >> 1, wn = w & 1;
    const int lr = l & 15, lk = l >> 4;

    f32x4 acc[4][6];
#pragma unroll
    for (int m = 0; m < 4; ++m)
#pragma unroll
        for (int n = 0; n < 6; ++n) acc[m][n] = f32x4{0.f, 0.f, 0.f, 0.f};

#pragma unroll
    for (int kk = 0; kk < 2; ++kk) {
        int kg = kk * 4 + lk;
        bf16x8 a[4], bb[6];
#pragma unroll
        for (int m = 0; m < 4; ++m) {
            int row = wm * 64 + m * 16 + lr;
            a[m] = *(const bf16x8*)&Pl[row * 64 + ((kg ^ (row & 7)) << 3)];
        }
#pragma unroll
        for (int n = 0; n < 6; ++n) {
            int col = wn * 96 + n * 16 + lr;
            bb[n] = *(const bf16x8*)&Rl[col * 64 + ((kg ^ (col & 7)) << 3)];
        }
#pragma unroll
        for (int m = 0; m < 4; ++m)
#pragma unroll
            for (int n = 0; n < 6; ++n)
                acc[m][n] = __builtin_amdgcn_mfma_f32_16x16x32_bf16(
                    a[m], bb[n], acc[m][n], 0, 0, 0);
    }

    uint16_t* Wb = Wt + ((size_t)b * OUTF + oh * 128) * INF;
#pragma unroll
    for (int m = 0; m < 4; ++m) {
        int o = wm * 64 + m * 16 + lk * 4;
#pragma unroll
        for (int n = 0; n < 6; ++n) {
            int i = wn * 96 + n * 16 + lr;
#pragma unroll
            for (int j = 0; j < 4; ++j)
                Wb[(size_t)(o + j) * INF + i] = f2bf(acc[m][n][j]);
        }
    }
}

// ---------------------------------------------------------------------------
// k2: 128(M) x 128(N) tile, 256 thr = 4 waves (2x2), wave 64x64, BK=32.
// As[3]: 128 rows x 128B, slot(16B) swizzle s' = s ^ (row&7)  -> 2-way (free)
// Bs[3]: 128 rows x  64B, slot(16B) swizzle s' = s ^ (row&3)  -> 4-way
// Staged via gl_lds, 6 loads/wave/stage (A:4 chunks + B:2 chunks), source
// pre-swizzled. Depth-2 pipeline: stage ks+2 in flight while computing ks;
// counted vmcnt(6) + one raw s_barrier per step. 72KB LDS -> 2 blocks/CU.
// Grid 2048 = b(128) x mt(8) x nt(2), bijective XCD swizzle (2048%8==0).
// ---------------------------------------------------------------------------
__global__ __launch_bounds__(256, 2) void k2_gemm(
    const float*    __restrict__ X,    // [128][1024][192]
    const uint16_t* __restrict__ Wt,   // [128][256][192] bf16
    float*          __restrict__ Y)    // [128][1024][256]
{
    __shared__ uint8_t  As[3][16384];  // 48 KB
    __shared__ uint16_t Bs[3][4096];   // 24 KB

    const int bid0 = blockIdx.x;
    const int bid  = ((bid0 & 7) << 8) | (bid0 >> 3);   // XCD swizzle
    const int b  = bid >> 4;
    const int mt = (bid >> 1) & 7;
    const int nt = bid & 1;
    const int t  = threadIdx.x, l = t & 63, w = t >> 6;

    const float*    Xb = X  + ((size_t)b * MPB  + mt * 128) * INF;
    const uint16_t* Wb = Wt + ((size_t)b * OUTF + nt * 128) * INF;
    float*          Yb = Y  + ((size_t)b * MPB  + mt * 128) * OUTF + nt * 128;

    // ---- staging source offsets (pre-swizzled; see header comment) ----
    // A chunk c = w*4+j : lane l covers row = c*8+(l>>3), lds slot = l&7,
    //   source slot = (l&7) ^ (l>>3)   (row&7 == l>>3)
    int aoff[4];
#pragma unroll
    for (int j = 0; j < 4; ++j) {
        int c = w * 4 + j;
        aoff[j] = (c * 8 + (l >> 3)) * INF + (((l & 7) ^ (l >> 3)) << 2);
    }
    // B chunk c = w*2+j : row = c*16+(l>>2), lds slot = l&3,
    //   source slot = (l&3) ^ ((l>>2)&3)
    int boff[2];
#pragma unroll
    for (int j = 0; j < 2; ++j) {
        int c = w * 2 + j;
        boff[j] = (c * 16 + (l >> 2)) * INF + (((l & 3) ^ ((l >> 2) & 3)) << 3);
    }

    auto stage = [&](int ks, int buf) {
#pragma unroll
        for (int j = 0; j < 4; ++j)
            gl_lds16(Xb + aoff[j] + ks * 32, &As[buf][(w * 4 + j) * 1024]);
#pragma unroll
        for (int j = 0; j < 2; ++j)
            gl_lds16(Wb + boff[j] + ks * 32, &Bs[buf][(w * 2 + j) * 512]);
    };

    stage(0, 0);
    stage(1, 1);

    const int wm = w >> 1, wn = w & 1;     // wave grid 2(M) x 2(N)
    const int lr = l & 15, lk = l >> 4;
    // read-side swizzled byte offsets within a row (lane constants)
    const int as0 = (((2 * lk)     ^ (lr & 7)) << 4);
    const int as1 = (((2 * lk + 1) ^ (lr & 7)) << 4);
    const int bs0 = ((lk ^ (lr & 3)) << 4);

    f32x4 acc[4][4];
#pragma unroll
    for (int m = 0; m < 4; ++m)
#pragma unroll
        for (int n = 0; n < 4; ++n) acc[m][n] = f32x4{0.f, 0.f, 0.f, 0.f};

#pragma unroll
    for (int ks = 0; ks < 6; ++ks) {
        const int cur = ks % 3;
        if (ks < 5) { WAIT_VM6(); } else { WAIT_VM0(); }
        __builtin_amdgcn_s_barrier();
        __builtin_amdgcn_sched_barrier(0);
        if (ks < 4) stage(ks + 2, (ks + 2) % 3);

        bf16x8 af[4], bfr[4];
#pragma unroll
        for (int m = 0; m < 4; ++m) {
            int row = wm * 64 + m * 16 + lr;
            const uint8_t* p = &As[cur][row * 128];
            f32x4 lo = *(const f32x4*)(p + as0);
            f32x4 hi = *(const f32x4*)(p + as1);
            af[m] = cvt8(lo, hi);
        }
#pragma unroll
        for (int n = 0; n < 4; ++n) {
            int rn = wn * 64 + n * 16 + lr;
            bfr[n] = *(const bf16x8*)((const uint8_t*)&Bs[cur][0] + rn * 64 + bs0);
        }
#pragma unroll
        for (int m = 0; m < 4; ++m)
#pragma unroll
            for (int n = 0; n < 4; ++n)
                acc[m][n] = __builtin_amdgcn_mfma_f32_16x16x32_bf16(
                    af[m], bfr[n], acc[m][n], 0, 0, 0);
    }

    // epilogue: D row=(lane>>4)*4+j, col=lane&15
#pragma unroll
    for (int m = 0; m < 4; ++m) {
        int r0 = wm * 64 + m * 16 + lk * 4;
#pragma unroll
        for (int n = 0; n < 4; ++n) {
            int c0 = wn * 64 + n * 16 + lr;
#pragma unroll
            for (int j = 0; j < 4; ++j)
                Yb[(size_t)(r0 + j) * OUTF + c0] = acc[m][n][j];
        }
    }
}

extern "C" void kernel_launch(void* const* d_in, const int* in_sizes, int n_in,
                              void* d_out, int out_size, void* d_ws, size_t ws_size,
                              hipStream_t stream) {
    (void)in_sizes; (void)n_in; (void)out_size; (void)ws_size;
    const float* state   = (const float*)d_in[0];
    const int*   session = (const int*)  d_in[1];
    const float* readin  = (const float*)d_in[2];
    const float* project = (const float*)d_in[3];
    float*    out = (float*)d_out;
    uint16_t* Wt  = (uint16_t*)d_ws;   // 128*256*192*2 B = 12.6 MB scratch

    hipLaunchKernelGGL(k1_build_w, dim3(256), dim3(256), 0, stream,
                       readin, project, session, Wt);
    hipLaunchKernelGGL(k2_gemm, dim3(2048), dim3(256), 0, stream,
                       state, Wt, out);
}